// Round 13
// baseline (305.976 us; speedup 1.0000x reference)
//
#include <hip/hip_runtime.h>
#include <hip/hip_bf16.h>
#include <stdint.h>

// Attention_65214783422545: B=4, S=1024, D=1024, H=16, dk=64
// PROBE ROUND: source identical to round 12; attn_kernel launched TWICE to
// expose its standalone duration as (dur_us - 201).  Idempotent & safe.
//
// Workspace layout (48 MB):
//   0   : xb   bf16 [4096][1024]            8 MB
//   8M  : wqkv bf16 [3072][1024]            6 MB   (Wq | Wk | Wv)
//   14M : wob  bf16 [1024][1024]            2 MB
//   16M : qbp  bf16 [64][1024][64] (scaled) 8 MB
//   24M : kbp  bf16 [64][1024][64]          8 MB
//   32M : vTb  bf16 [64][64][1024]          8 MB
//   40M : yh   bf16 [4096][1024]            8 MB

typedef short short8 __attribute__((ext_vector_type(8)));
typedef short short4v __attribute__((ext_vector_type(4)));
typedef float f32x4 __attribute__((ext_vector_type(4)));

__device__ __forceinline__ short f2bf(float f) {
    union { __hip_bfloat16 h; short s; } u;
    u.h = __float2bfloat16(f);
    return u.s;
}
__device__ __forceinline__ float bf2f(short s) {
    union { uint32_t u; float f; } c;
    c.u = ((uint32_t)(uint16_t)s) << 16;
    return c.f;
}

#define GLD16(g, l) __builtin_amdgcn_global_load_lds( \
    (const __attribute__((address_space(1))) void*)(g), \
    (__attribute__((address_space(3))) void*)(l), 16, 0, 0)

// ---------------- cast all fp32 inputs -> bf16, one launch ----------------
__global__ __launch_bounds__(256) void castall_kernel(const float* __restrict__ x,
                                                      const float* __restrict__ w0,
                                                      const float* __restrict__ w1,
                                                      const float* __restrict__ w2,
                                                      const float* __restrict__ w3,
                                                      short* __restrict__ xb,
                                                      short* __restrict__ qkv,
                                                      short* __restrict__ wo) {
    const int seg = blockIdx.y;
    const float* src;
    short* dst;
    if (seg < 4) {
        src = seg == 0 ? w0 : seg == 1 ? w1 : seg == 2 ? w2 : w3;
        dst = seg < 3 ? qkv + (size_t)seg * 1048576 : wo;
    } else {
        src = x + (size_t)(seg - 4) * 1048576;
        dst = xb + (size_t)(seg - 4) * 1048576;
    }
    for (int i = blockIdx.x * 256 + threadIdx.x; i < 262144; i += gridDim.x * 256) {
        float4 v = ((const float4*)src)[i];
        short4v o;
        o[0] = f2bf(v.x); o[1] = f2bf(v.y); o[2] = f2bf(v.z); o[3] = f2bf(v.w);
        ((short4v*)dst)[i] = o;
    }
}

// ---------------- GEMM (round-11 dbuf structure) ----------------
__global__ __launch_bounds__(256) void gemm_bt(const short* __restrict__ A,
                                               const short* __restrict__ Bw,
                                               const float* __restrict__ b0,
                                               const float* __restrict__ b1,
                                               const float* __restrict__ b2,
                                               short* __restrict__ outq,
                                               short* __restrict__ outk,
                                               short* __restrict__ outv,
                                               float* __restrict__ fout,
                                               int mode) {
    __shared__ __align__(16) short As[2][128 * 32];
    __shared__ __align__(16) short Bs[2][128 * 32];

    const int tid = threadIdx.x;
    const int wave = tid >> 6, lane = tid & 63;
    const int l15 = lane & 15, l4 = lane >> 4;
    const int wm = wave >> 1, wn = wave & 1;
    const int tM = blockIdx.y * 128, tN = blockIdx.x * 128;

    f32x4 acc[4][4] = {};

    auto stage = [&](int buf, int kt) {
        #pragma unroll
        for (int rep = 0; rep < 2; ++rep) {
            int slot = (wave * 2 + rep) * 64 + lane;
            int e0 = slot * 8;
            int row = e0 >> 5, col = e0 & 31;
            GLD16(&A[(size_t)(tM + row) * 1024 + kt + col],
                  (char*)&As[buf][0] + (size_t)(wave * 2 + rep) * 1024);
            GLD16(&Bw[(size_t)(tN + row) * 1024 + kt + col],
                  (char*)&Bs[buf][0] + (size_t)(wave * 2 + rep) * 1024);
        }
    };

    stage(0, 0);
    __syncthreads();
    int cur = 0;

    for (int t = 0; t < 32; ++t) {
        if (t < 31) stage(cur ^ 1, (t + 1) * 32);

        short8 af[4], bfr[4];
        #pragma unroll
        for (int f = 0; f < 4; ++f) {
            af[f]  = *(const short8*)&As[cur][(wm * 64 + f * 16 + l15) * 32 + l4 * 8];
            bfr[f] = *(const short8*)&Bs[cur][(wn * 64 + f * 16 + l15) * 32 + l4 * 8];
        }
        #pragma unroll
        for (int i = 0; i < 4; ++i)
            #pragma unroll
            for (int j = 0; j < 4; ++j)
                acc[i][j] = __builtin_amdgcn_mfma_f32_16x16x32_bf16(af[i], bfr[j], acc[i][j], 0, 0, 0);

        __syncthreads();
        cur ^= 1;
    }

    const int seg = tN >> 10;
    const float* bias = (mode == 3) ? b0 : (seg == 0 ? b0 : seg == 1 ? b1 : b2);

    #pragma unroll
    for (int i = 0; i < 4; ++i) {
        #pragma unroll
        for (int j = 0; j < 4; ++j) {
            if (mode == 4 && seg == 2) {
                int gr0 = tM + wm * 64 + i * 16 + l4 * 4;
                int gc  = tN + wn * 64 + j * 16 + l15;
                int nloc = gc & 1023;
                int bb = gr0 >> 10, s0 = gr0 & 1023, h = nloc >> 6, dk = nloc & 63;
                float bv_ = bias[nloc];
                short4v pk;
                #pragma unroll
                for (int v = 0; v < 4; ++v) pk[v] = f2bf(acc[i][j][v] + bv_);
                *(short4v*)&outv[(((size_t)bb * 16 + h) * 64 + dk) * 1024 + s0] = pk;
            } else {
                #pragma unroll
                for (int v = 0; v < 4; ++v) {
                    int gr = tM + wm * 64 + i * 16 + l4 * 4 + v;
                    int gc = tN + wn * 64 + j * 16 + l15;
                    if (mode == 3) {
                        fout[(size_t)gr * 1024 + gc] = acc[i][j][v] + bias[gc];
                    } else {
                        int nloc = gc & 1023;
                        float val = acc[i][j][v] + bias[nloc];
                        int bb = gr >> 10, s = gr & 1023, h = nloc >> 6, dk = nloc & 63;
                        if (seg == 0) {
                            outq[(((size_t)bb * 16 + h) * 1024 + s) * 64 + dk] = f2bf(val * 0.125f);
                        } else {
                            outk[(((size_t)bb * 16 + h) * 1024 + s) * 64 + dk] = f2bf(val);
                        }
                    }
                }
            }
        }
    }
}

// ---------------- fused attention (round-12 body) ----------------
__global__ __launch_bounds__(512, 4) void attn_kernel(const short* __restrict__ q,
                                                      const short* __restrict__ k,
                                                      const short* __restrict__ vT,
                                                      float* __restrict__ attn,
                                                      short* __restrict__ yh) {
    const int bh = blockIdx.x;
    const int y = blockIdx.y;
    const int qb = (y & 1) ? (31 - (y >> 1)) : (y >> 1);
    const int tid = threadIdx.x;
    const int wave = tid >> 6, lane = tid & 63;
    const int l15 = lane & 15, l4 = lane >> 4;
    const int rg = wave & 1, cg = wave >> 1;
    const int q0 = qb * 32;
    const int rbase = q0 + rg * 16;
    const int c0w = cg * 256;

    __shared__ __align__(16) short pb[32][1032];
    __shared__ float mred[4][32];
    __shared__ float sred[4][32];

    short8 qf[2];
    {
        const short* qrow = q + ((size_t)bh * 1024 + rbase + l15) * 64;
        qf[0] = *(const short8*)(qrow + l4 * 8);
        qf[1] = *(const short8*)(qrow + 32 + l4 * 8);
    }

    f32x4 sc[16] = {};
    #pragma unroll
    for (int cf = 0; cf < 16; ++cf) {
        if (c0w + cf * 16 < rbase + 16) {
            const short* krow = k + ((size_t)bh * 1024 + c0w + cf * 16 + l15) * 64;
            short8 kf0 = *(const short8*)(krow + l4 * 8);
            short8 kf1 = *(const short8*)(krow + 32 + l4 * 8);
            sc[cf] = __builtin_amdgcn_mfma_f32_16x16x32_bf16(qf[0], kf0, sc[cf], 0, 0, 0);
            sc[cf] = __builtin_amdgcn_mfma_f32_16x16x32_bf16(qf[1], kf1, sc[cf], 0, 0, 0);
        }
    }

    float mrow[4];
    #pragma unroll
    for (int j = 0; j < 4; ++j) {
        int rglob = rbase + l4 * 4 + j;
        float m = -1e30f;
        #pragma unroll
        for (int cf = 0; cf < 16; ++cf) {
            int col = c0w + cf * 16 + l15;
            m = fmaxf(m, (col <= rglob) ? sc[cf][j] : -1e30f);
        }
        m = fmaxf(m, __shfl_xor(m, 1));
        m = fmaxf(m, __shfl_xor(m, 2));
        m = fmaxf(m, __shfl_xor(m, 4));
        m = fmaxf(m, __shfl_xor(m, 8));
        mrow[j] = m;
    }
    if (l15 == 0) {
        #pragma unroll
        for (int j = 0; j < 4; ++j) mred[cg][rg * 16 + l4 * 4 + j] = mrow[j];
    }
    __syncthreads();
    #pragma unroll
    for (int j = 0; j < 4; ++j) {
        int r = rg * 16 + l4 * 4 + j;
        mrow[j] = fmaxf(fmaxf(mred[0][r], mred[1][r]), fmaxf(mred[2][r], mred[3][r]));
    }

    float inv[4], ls[4];
    #pragma unroll
    for (int j = 0; j < 4; ++j) {
        int rglob = rbase + l4 * 4 + j;
        float s = 0.f;
        #pragma unroll
        for (int cf = 0; cf < 16; ++cf) {
            int col = c0w + cf * 16 + l15;
            float e = (col <= rglob) ? __expf(sc[cf][j] - mrow[j]) : 0.f;
            sc[cf][j] = e;
            s += e;
        }
        s += __shfl_xor(s, 1);
        s += __shfl_xor(s, 2);
        s += __shfl_xor(s, 4);
        s += __shfl_xor(s, 8);
        ls[j] = s;
    }
    if (l15 == 0) {
        #pragma unroll
        for (int j = 0; j < 4; ++j) sred[cg][rg * 16 + l4 * 4 + j] = ls[j];
    }
    __syncthreads();
    #pragma unroll
    for (int j = 0; j < 4; ++j) {
        int r = rg * 16 + l4 * 4 + j;
        inv[j] = 1.0f / (sred[0][r] + sred[1][r] + sred[2][r] + sred[3][r]);
    }

    {
        float* abase = attn + (size_t)bh * 1048576;
        #pragma unroll
        for (int cf = 0; cf < 16; ++cf) {
            const bool keep = (c0w + cf * 16 < q0 + 64);
            const int col = c0w + cf * 16 + l15;
            #pragma unroll
            for (int j = 0; j < 4; ++j) {
                const int row = rg * 16 + l4 * 4 + j;
                float p = sc[cf][j] * inv[j];
                __builtin_nontemporal_store(p, &abase[(size_t)(q0 + row) * 1024 + col]);
                if (keep) pb[row][col] = f2bf(p);
            }
        }
    }
    __syncthreads();

    f32x4 yacc = {};
    {
        const short* vrow = vT + ((size_t)bh * 64 + cg * 16 + l15) * 1024;
        const int nch = (rbase + 16 + 31) >> 5;
        for (int ks = 0; ks < nch; ++ks) {
            short8 pf = *(const short8*)&pb[rg * 16 + l15][ks * 32 + l4 * 8];
            short8 vf = *(const short8*)(vrow + ks * 32 + l4 * 8);
            yacc = __builtin_amdgcn_mfma_f32_16x16x32_bf16(pf, vf, yacc, 0, 0, 0);
        }
    }

    const int b = bh >> 4, h = bh & 15;
    #pragma unroll
    for (int j = 0; j < 4; ++j) {
        yh[((size_t)b * 1024 + rbase + l4 * 4 + j) * 1024 + h * 64 + cg * 16 + l15] = f2bf(yacc[j]);
    }
}

extern "C" void kernel_launch(void* const* d_in, const int* in_sizes, int n_in,
                              void* d_out, int out_size, void* d_ws, size_t ws_size,
                              hipStream_t stream) {
    const float* x  = (const float*)d_in[0];
    const float* Wq = (const float*)d_in[1];
    const float* bq = (const float*)d_in[2];
    const float* Wk = (const float*)d_in[3];
    const float* bk = (const float*)d_in[4];
    const float* Wv = (const float*)d_in[5];
    const float* bv = (const float*)d_in[6];
    const float* Wo = (const float*)d_in[7];
    const float* bo = (const float*)d_in[8];

    char* ws = (char*)d_ws;
    short* xb   = (short*)(ws + ((size_t)0 << 20));
    short* wqkv = (short*)(ws + ((size_t)8 << 20));
    short* wob  = (short*)(ws + ((size_t)14 << 20));
    short* qbp  = (short*)(ws + ((size_t)16 << 20));
    short* kbp  = (short*)(ws + ((size_t)24 << 20));
    short* vTb  = (short*)(ws + ((size_t)32 << 20));
    short* yh   = (short*)(ws + ((size_t)40 << 20));

    float* attn = (float*)d_out;
    float* yout = attn + (size_t)67108864;

    castall_kernel<<<dim3(128, 8), 256, 0, stream>>>(x, Wq, Wk, Wv, Wo, xb, wqkv, wob);

    gemm_bt<<<dim3(24, 32), 256, 0, stream>>>(xb, wqkv, bq, bk, bv, qbp, kbp, vTb, nullptr, 4);

    // PROBE: attn launched twice; second is idempotent. dur_us - 201 = T_attn.
    attn_kernel<<<dim3(64, 32), 512, 0, stream>>>(qbp, kbp, vTb, attn, yh);
    attn_kernel<<<dim3(64, 32), 512, 0, stream>>>(qbp, kbp, vTb, attn, yh);

    gemm_bt<<<dim3(8, 32), 256, 0, stream>>>(yh, wob, bo, bo, bo, nullptr, nullptr, nullptr, yout, 3);
}

// Round 14
// 194.856 us; speedup vs baseline: 1.5703x; 1.5703x over previous
//
#include <hip/hip_runtime.h>
#include <hip/hip_bf16.h>
#include <stdint.h>

// Attention_65214783422545: B=4, S=1024, D=1024, H=16, dk=64
// outputs: attn_w [4,16,1024,1024] fp32 then y [4,1024,1024] fp32
//
// Workspace layout (48 MB):
//   0   : xb   bf16 [4096][1024]            8 MB
//   8M  : wqkv bf16 [3072][1024]            6 MB   (Wq | Wk | Wv)
//   14M : wob  bf16 [1024][1024]            2 MB
//   16M : qbp  bf16 [64][1024][64] (scaled) 8 MB
//   24M : kbp  bf16 [64][1024][64]          8 MB
//   32M : vTb  bf16 [64][64][1024]          8 MB
//   40M : yh   bf16 [4096][1024]            8 MB

typedef short short8 __attribute__((ext_vector_type(8)));
typedef short short4v __attribute__((ext_vector_type(4)));
typedef float f32x4 __attribute__((ext_vector_type(4)));

__device__ __forceinline__ short f2bf(float f) {
    union { __hip_bfloat16 h; short s; } u;
    u.h = __float2bfloat16(f);
    return u.s;
}
__device__ __forceinline__ float bf2f(short s) {
    union { uint32_t u; float f; } c;
    c.u = ((uint32_t)(uint16_t)s) << 16;
    return c.f;
}

#define GLD16(g, l) __builtin_amdgcn_global_load_lds( \
    (const __attribute__((address_space(1))) void*)(g), \
    (__attribute__((address_space(3))) void*)(l), 16, 0, 0)

// ---------------- cast all fp32 inputs -> bf16, one launch ----------------
__global__ __launch_bounds__(256) void castall_kernel(const float* __restrict__ x,
                                                      const float* __restrict__ w0,
                                                      const float* __restrict__ w1,
                                                      const float* __restrict__ w2,
                                                      const float* __restrict__ w3,
                                                      short* __restrict__ xb,
                                                      short* __restrict__ qkv,
                                                      short* __restrict__ wo) {
    const int seg = blockIdx.y;
    const float* src;
    short* dst;
    if (seg < 4) {
        src = seg == 0 ? w0 : seg == 1 ? w1 : seg == 2 ? w2 : w3;
        dst = seg < 3 ? qkv + (size_t)seg * 1048576 : wo;
    } else {
        src = x + (size_t)(seg - 4) * 1048576;
        dst = xb + (size_t)(seg - 4) * 1048576;
    }
    for (int i = blockIdx.x * 256 + threadIdx.x; i < 262144; i += gridDim.x * 256) {
        float4 v = ((const float4*)src)[i];
        short4v o;
        o[0] = f2bf(v.x); o[1] = f2bf(v.y); o[2] = f2bf(v.z); o[3] = f2bf(v.w);
        ((short4v*)dst)[i] = o;
    }
}

// ---------------- QKV GEMM, 256x256 tile ----------------
// C[4096,3072] = xb[4096,1024] @ wqkv[3072,1024]^T + bias(seg).
// 512 threads = 8 waves (2 Mgroups x 4 Ngroups); per-wave 128x64 out.
// 2-phase dbuf; 1D grid 192 blocks, bijective XCD swizzle (192%8==0);
// by = swz%16 (M), bx = swz/16 (N) -> per-XCD B-panel ~L2-resident.
__global__ __launch_bounds__(512, 2) void gemm_qkv256(const short* __restrict__ A,
                                                      const short* __restrict__ Bw,
                                                      const float* __restrict__ b0,
                                                      const float* __restrict__ b1,
                                                      const float* __restrict__ b2,
                                                      short* __restrict__ outq,
                                                      short* __restrict__ outk,
                                                      short* __restrict__ outv) {
    __shared__ __align__(16) short As[2][256 * 32];
    __shared__ __align__(16) short Bs[2][256 * 32];

    const int tid = threadIdx.x;
    const int wave = tid >> 6, lane = tid & 63;
    const int l15 = lane & 15, l4 = lane >> 4;
    const int wm = wave >> 2, wn = wave & 3;

    const int lin = blockIdx.x;                 // 0..191
    const int swz = (lin & 7) * 24 + (lin >> 3);  // bijective XCD chunk map
    const int by = swz & 15, bx = swz >> 4;     // by: M (16), bx: N (12)
    const int tM = by * 256, tN = bx * 256;

    f32x4 acc[8][4] = {};

    auto stage = [&](int buf, int kt) {
        #pragma unroll
        for (int rep = 0; rep < 2; ++rep) {
            int slot = (wave * 2 + rep) * 64 + lane;
            int e0 = slot * 8;
            int row = e0 >> 5, col = e0 & 31;
            GLD16(&A[(size_t)(tM + row) * 1024 + kt + col],
                  (char*)&As[buf][0] + (size_t)(wave * 2 + rep) * 1024);
            GLD16(&Bw[(size_t)(tN + row) * 1024 + kt + col],
                  (char*)&Bs[buf][0] + (size_t)(wave * 2 + rep) * 1024);
        }
    };

    stage(0, 0);
    __syncthreads();
    int cur = 0;

    for (int t = 0; t < 32; ++t) {
        if (t < 31) stage(cur ^ 1, (t + 1) * 32);

        short8 af[8], bfr[4];
        #pragma unroll
        for (int f = 0; f < 8; ++f)
            af[f] = *(const short8*)&As[cur][(wm * 128 + f * 16 + l15) * 32 + l4 * 8];
        #pragma unroll
        for (int f = 0; f < 4; ++f)
            bfr[f] = *(const short8*)&Bs[cur][(wn * 64 + f * 16 + l15) * 32 + l4 * 8];

        #pragma unroll
        for (int i = 0; i < 8; ++i)
            #pragma unroll
            for (int j = 0; j < 4; ++j)
                acc[i][j] = __builtin_amdgcn_mfma_f32_16x16x32_bf16(af[i], bfr[j], acc[i][j], 0, 0, 0);

        __syncthreads();
        cur ^= 1;
    }

    const int seg = tN >> 10;   // block-uniform (256 | 1024)
    const float* bias = seg == 0 ? b0 : seg == 1 ? b1 : b2;

    #pragma unroll
    for (int i = 0; i < 8; ++i) {
        #pragma unroll
        for (int j = 0; j < 4; ++j) {
            int gc = tN + wn * 64 + j * 16 + l15;
            int nloc = gc & 1023;
            int h = nloc >> 6, dk = nloc & 63;
            float bv_ = bias[nloc];
            if (seg == 2) {
                int gr0 = tM + wm * 128 + i * 16 + l4 * 4;
                int bb = gr0 >> 10, s0 = gr0 & 1023;
                short4v pk;
                #pragma unroll
                for (int v = 0; v < 4; ++v) pk[v] = f2bf(acc[i][j][v] + bv_);
                *(short4v*)&outv[(((size_t)bb * 16 + h) * 64 + dk) * 1024 + s0] = pk;
            } else {
                #pragma unroll
                for (int v = 0; v < 4; ++v) {
                    int gr = tM + wm * 128 + i * 16 + l4 * 4 + v;
                    int bb = gr >> 10, s = gr & 1023;
                    float val = acc[i][j][v] + bv_;
                    if (seg == 0) {
                        outq[(((size_t)bb * 16 + h) * 1024 + s) * 64 + dk] = f2bf(val * 0.125f);
                    } else {
                        outk[(((size_t)bb * 16 + h) * 1024 + s) * 64 + dk] = f2bf(val);
                    }
                }
            }
        }
    }
}

// ---------------- O-proj GEMM (round-11 dbuf 128² structure) ----------------
__global__ __launch_bounds__(256) void gemm_o(const short* __restrict__ A,
                                              const short* __restrict__ Bw,
                                              const float* __restrict__ bias,
                                              float* __restrict__ fout) {
    __shared__ __align__(16) short As[2][128 * 32];
    __shared__ __align__(16) short Bs[2][128 * 32];

    const int tid = threadIdx.x;
    const int wave = tid >> 6, lane = tid & 63;
    const int l15 = lane & 15, l4 = lane >> 4;
    const int wm = wave >> 1, wn = wave & 1;
    const int tM = blockIdx.y * 128, tN = blockIdx.x * 128;

    f32x4 acc[4][4] = {};

    auto stage = [&](int buf, int kt) {
        #pragma unroll
        for (int rep = 0; rep < 2; ++rep) {
            int slot = (wave * 2 + rep) * 64 + lane;
            int e0 = slot * 8;
            int row = e0 >> 5, col = e0 & 31;
            GLD16(&A[(size_t)(tM + row) * 1024 + kt + col],
                  (char*)&As[buf][0] + (size_t)(wave * 2 + rep) * 1024);
            GLD16(&Bw[(size_t)(tN + row) * 1024 + kt + col],
                  (char*)&Bs[buf][0] + (size_t)(wave * 2 + rep) * 1024);
        }
    };

    stage(0, 0);
    __syncthreads();
    int cur = 0;

    for (int t = 0; t < 32; ++t) {
        if (t < 31) stage(cur ^ 1, (t + 1) * 32);

        short8 af[4], bfr[4];
        #pragma unroll
        for (int f = 0; f < 4; ++f) {
            af[f]  = *(const short8*)&As[cur][(wm * 64 + f * 16 + l15) * 32 + l4 * 8];
            bfr[f] = *(const short8*)&Bs[cur][(wn * 64 + f * 16 + l15) * 32 + l4 * 8];
        }
        #pragma unroll
        for (int i = 0; i < 4; ++i)
            #pragma unroll
            for (int j = 0; j < 4; ++j)
                acc[i][j] = __builtin_amdgcn_mfma_f32_16x16x32_bf16(af[i], bfr[j], acc[i][j], 0, 0, 0);

        __syncthreads();
        cur ^= 1;
    }

    #pragma unroll
    for (int i = 0; i < 4; ++i) {
        #pragma unroll
        for (int j = 0; j < 4; ++j) {
            #pragma unroll
            for (int v = 0; v < 4; ++v) {
                int gr = tM + wm * 64 + i * 16 + l4 * 4 + v;
                int gc = tN + wn * 64 + j * 16 + l15;
                fout[(size_t)gr * 1024 + gc] = acc[i][j][v] + bias[gc];
            }
        }
    }
}

// ---------------- fused attention (round-12 body, verified 105 µs) ----------
__global__ __launch_bounds__(512, 4) void attn_kernel(const short* __restrict__ q,
                                                      const short* __restrict__ k,
                                                      const short* __restrict__ vT,
                                                      float* __restrict__ attn,
                                                      short* __restrict__ yh) {
    const int bh = blockIdx.x;
    const int y = blockIdx.y;
    const int qb = (y & 1) ? (31 - (y >> 1)) : (y >> 1);
    const int tid = threadIdx.x;
    const int wave = tid >> 6, lane = tid & 63;
    const int l15 = lane & 15, l4 = lane >> 4;
    const int rg = wave & 1, cg = wave >> 1;
    const int q0 = qb * 32;
    const int rbase = q0 + rg * 16;
    const int c0w = cg * 256;

    __shared__ __align__(16) short pb[32][1032];
    __shared__ float mred[4][32];
    __shared__ float sred[4][32];

    short8 qf[2];
    {
        const short* qrow = q + ((size_t)bh * 1024 + rbase + l15) * 64;
        qf[0] = *(const short8*)(qrow + l4 * 8);
        qf[1] = *(const short8*)(qrow + 32 + l4 * 8);
    }

    f32x4 sc[16] = {};
    #pragma unroll
    for (int cf = 0; cf < 16; ++cf) {
        if (c0w + cf * 16 < rbase + 16) {
            const short* krow = k + ((size_t)bh * 1024 + c0w + cf * 16 + l15) * 64;
            short8 kf0 = *(const short8*)(krow + l4 * 8);
            short8 kf1 = *(const short8*)(krow + 32 + l4 * 8);
            sc[cf] = __builtin_amdgcn_mfma_f32_16x16x32_bf16(qf[0], kf0, sc[cf], 0, 0, 0);
            sc[cf] = __builtin_amdgcn_mfma_f32_16x16x32_bf16(qf[1], kf1, sc[cf], 0, 0, 0);
        }
    }

    float mrow[4];
    #pragma unroll
    for (int j = 0; j < 4; ++j) {
        int rglob = rbase + l4 * 4 + j;
        float m = -1e30f;
        #pragma unroll
        for (int cf = 0; cf < 16; ++cf) {
            int col = c0w + cf * 16 + l15;
            m = fmaxf(m, (col <= rglob) ? sc[cf][j] : -1e30f);
        }
        m = fmaxf(m, __shfl_xor(m, 1));
        m = fmaxf(m, __shfl_xor(m, 2));
        m = fmaxf(m, __shfl_xor(m, 4));
        m = fmaxf(m, __shfl_xor(m, 8));
        mrow[j] = m;
    }
    if (l15 == 0) {
        #pragma unroll
        for (int j = 0; j < 4; ++j) mred[cg][rg * 16 + l4 * 4 + j] = mrow[j];
    }
    __syncthreads();
    #pragma unroll
    for (int j = 0; j < 4; ++j) {
        int r = rg * 16 + l4 * 4 + j;
        mrow[j] = fmaxf(fmaxf(mred[0][r], mred[1][r]), fmaxf(mred[2][r], mred[3][r]));
    }

    float inv[4], ls[4];
    #pragma unroll
    for (int j = 0; j < 4; ++j) {
        int rglob = rbase + l4 * 4 + j;
        float s = 0.f;
        #pragma unroll
        for (int cf = 0; cf < 16; ++cf) {
            int col = c0w + cf * 16 + l15;
            float e = (col <= rglob) ? __expf(sc[cf][j] - mrow[j]) : 0.f;
            sc[cf][j] = e;
            s += e;
        }
        s += __shfl_xor(s, 1);
        s += __shfl_xor(s, 2);
        s += __shfl_xor(s, 4);
        s += __shfl_xor(s, 8);
        ls[j] = s;
    }
    if (l15 == 0) {
        #pragma unroll
        for (int j = 0; j < 4; ++j) sred[cg][rg * 16 + l4 * 4 + j] = ls[j];
    }
    __syncthreads();
    #pragma unroll
    for (int j = 0; j < 4; ++j) {
        int r = rg * 16 + l4 * 4 + j;
        inv[j] = 1.0f / (sred[0][r] + sred[1][r] + sred[2][r] + sred[3][r]);
    }

    {
        float* abase = attn + (size_t)bh * 1048576;
        #pragma unroll
        for (int cf = 0; cf < 16; ++cf) {
            const bool keep = (c0w + cf * 16 < q0 + 64);
            const int col = c0w + cf * 16 + l15;
            #pragma unroll
            for (int j = 0; j < 4; ++j) {
                const int row = rg * 16 + l4 * 4 + j;
                float p = sc[cf][j] * inv[j];
                __builtin_nontemporal_store(p, &abase[(size_t)(q0 + row) * 1024 + col]);
                if (keep) pb[row][col] = f2bf(p);
            }
        }
    }
    __syncthreads();

    f32x4 yacc = {};
    {
        const short* vrow = vT + ((size_t)bh * 64 + cg * 16 + l15) * 1024;
        const int nch = (rbase + 16 + 31) >> 5;
        for (int ks = 0; ks < nch; ++ks) {
            short8 pf = *(const short8*)&pb[rg * 16 + l15][ks * 32 + l4 * 8];
            short8 vf = *(const short8*)(vrow + ks * 32 + l4 * 8);
            yacc = __builtin_amdgcn_mfma_f32_16x16x32_bf16(pf, vf, yacc, 0, 0, 0);
        }
    }

    const int b = bh >> 4, h = bh & 15;
    #pragma unroll
    for (int j = 0; j < 4; ++j) {
        yh[((size_t)b * 1024 + rbase + l4 * 4 + j) * 1024 + h * 64 + cg * 16 + l15] = f2bf(yacc[j]);
    }
}

extern "C" void kernel_launch(void* const* d_in, const int* in_sizes, int n_in,
                              void* d_out, int out_size, void* d_ws, size_t ws_size,
                              hipStream_t stream) {
    const float* x  = (const float*)d_in[0];
    const float* Wq = (const float*)d_in[1];
    const float* bq = (const float*)d_in[2];
    const float* Wk = (const float*)d_in[3];
    const float* bk = (const float*)d_in[4];
    const float* Wv = (const float*)d_in[5];
    const float* bv = (const float*)d_in[6];
    const float* Wo = (const float*)d_in[7];
    const float* bo = (const float*)d_in[8];

    char* ws = (char*)d_ws;
    short* xb   = (short*)(ws + ((size_t)0 << 20));
    short* wqkv = (short*)(ws + ((size_t)8 << 20));
    short* wob  = (short*)(ws + ((size_t)14 << 20));
    short* qbp  = (short*)(ws + ((size_t)16 << 20));
    short* kbp  = (short*)(ws + ((size_t)24 << 20));
    short* vTb  = (short*)(ws + ((size_t)32 << 20));
    short* yh   = (short*)(ws + ((size_t)40 << 20));

    float* attn = (float*)d_out;
    float* yout = attn + (size_t)67108864;

    castall_kernel<<<dim3(128, 8), 256, 0, stream>>>(x, Wq, Wk, Wv, Wo, xb, wqkv, wob);

    gemm_qkv256<<<192, 512, 0, stream>>>(xb, wqkv, bq, bk, bv, qbp, kbp, vTb);

    attn_kernel<<<dim3(64, 32), 512, 0, stream>>>(qbp, kbp, vTb, attn, yh);

    gemm_o<<<dim3(8, 32), 256, 0, stream>>>(yh, wob, bo, yout);
}

// Round 15
// 192.354 us; speedup vs baseline: 1.5907x; 1.0130x over previous
//
#include <hip/hip_runtime.h>
#include <hip/hip_bf16.h>
#include <stdint.h>

// Attention_65214783422545: B=4, S=1024, D=1024, H=16, dk=64
// outputs: attn_w [4,16,1024,1024] fp32 then y [4,1024,1024] fp32
//
// Workspace layout (48 MB):
//   0   : xb   bf16 [4096][1024]            8 MB
//   8M  : wqkv bf16 [3072][1024]            6 MB   (Wq | Wk | Wv)
//   14M : wob  bf16 [1024][1024]            2 MB
//   16M : qbp  bf16 [64][1024][64] (scaled) 8 MB
//   24M : kbp  bf16 [64][1024][64]          8 MB
//   32M : vTb  bf16 [64][64][1024]          8 MB
//   40M : yh   bf16 [4096][1024]            8 MB

typedef short short8 __attribute__((ext_vector_type(8)));
typedef short short4v __attribute__((ext_vector_type(4)));
typedef float f32x4 __attribute__((ext_vector_type(4)));

__device__ __forceinline__ short f2bf(float f) {
    union { __hip_bfloat16 h; short s; } u;
    u.h = __float2bfloat16(f);
    return u.s;
}
__device__ __forceinline__ float bf2f(short s) {
    union { uint32_t u; float f; } c;
    c.u = ((uint32_t)(uint16_t)s) << 16;
    return c.f;
}

#define GLD16(g, l) __builtin_amdgcn_global_load_lds( \
    (const __attribute__((address_space(1))) void*)(g), \
    (__attribute__((address_space(3))) void*)(l), 16, 0, 0)

// ---------------- cast all fp32 inputs -> bf16, one launch ----------------
__global__ __launch_bounds__(256) void castall_kernel(const float* __restrict__ x,
                                                      const float* __restrict__ w0,
                                                      const float* __restrict__ w1,
                                                      const float* __restrict__ w2,
                                                      const float* __restrict__ w3,
                                                      short* __restrict__ xb,
                                                      short* __restrict__ qkv,
                                                      short* __restrict__ wo) {
    const int seg = blockIdx.y;
    const float* src;
    short* dst;
    if (seg < 4) {
        src = seg == 0 ? w0 : seg == 1 ? w1 : seg == 2 ? w2 : w3;
        dst = seg < 3 ? qkv + (size_t)seg * 1048576 : wo;
    } else {
        src = x + (size_t)(seg - 4) * 1048576;
        dst = xb + (size_t)(seg - 4) * 1048576;
    }
    for (int i = blockIdx.x * 256 + threadIdx.x; i < 262144; i += gridDim.x * 256) {
        float4 v = ((const float4*)src)[i];
        short4v o;
        o[0] = f2bf(v.x); o[1] = f2bf(v.y); o[2] = f2bf(v.z); o[3] = f2bf(v.w);
        ((short4v*)dst)[i] = o;
    }
}

// ---------------- QKV GEMM, 256x256 tile, 16 waves ----------------
// C[4096,3072] = xb @ wqkv^T + bias(seg). 1024 thr = 16 waves (4M x 4N),
// per-wave 64x64 out -> acc[4][4] (~115 VGPR) -> 16 waves/CU (2x round-14).
// 2-phase dbuf; 1 GLD16/lane/matrix per tile; bijective XCD swizzle.
__global__ __launch_bounds__(1024, 1) void gemm_qkv256(const short* __restrict__ A,
                                                       const short* __restrict__ Bw,
                                                       const float* __restrict__ b0,
                                                       const float* __restrict__ b1,
                                                       const float* __restrict__ b2,
                                                       short* __restrict__ outq,
                                                       short* __restrict__ outk,
                                                       short* __restrict__ outv) {
    __shared__ __align__(16) short As[2][256 * 32];
    __shared__ __align__(16) short Bs[2][256 * 32];

    const int tid = threadIdx.x;
    const int wave = tid >> 6, lane = tid & 63;
    const int l15 = lane & 15, l4 = lane >> 4;
    const int wm = wave >> 2, wn = wave & 3;

    const int lin = blockIdx.x;                   // 0..191
    const int swz = (lin & 7) * 24 + (lin >> 3);  // bijective (192 % 8 == 0)
    const int by = swz & 15, bx = swz >> 4;       // M(16) x N(12)
    const int tM = by * 256, tN = bx * 256;

    f32x4 acc[4][4] = {};

    auto stage = [&](int buf, int kt) {
        int e0 = tid * 8;
        int row = e0 >> 5, col = e0 & 31;
        GLD16(&A[(size_t)(tM + row) * 1024 + kt + col],
              (char*)&As[buf][0] + (size_t)tid * 16);
        GLD16(&Bw[(size_t)(tN + row) * 1024 + kt + col],
              (char*)&Bs[buf][0] + (size_t)tid * 16);
    };

    stage(0, 0);
    __syncthreads();
    int cur = 0;

    for (int t = 0; t < 32; ++t) {
        if (t < 31) stage(cur ^ 1, (t + 1) * 32);

        short8 af[4], bfr[4];
        #pragma unroll
        for (int f = 0; f < 4; ++f) {
            af[f]  = *(const short8*)&As[cur][(wm * 64 + f * 16 + l15) * 32 + l4 * 8];
            bfr[f] = *(const short8*)&Bs[cur][(wn * 64 + f * 16 + l15) * 32 + l4 * 8];
        }
        #pragma unroll
        for (int i = 0; i < 4; ++i)
            #pragma unroll
            for (int j = 0; j < 4; ++j)
                acc[i][j] = __builtin_amdgcn_mfma_f32_16x16x32_bf16(af[i], bfr[j], acc[i][j], 0, 0, 0);

        __syncthreads();
        cur ^= 1;
    }

    const int seg = tN >> 10;   // block-uniform
    const float* bias = seg == 0 ? b0 : seg == 1 ? b1 : b2;

    #pragma unroll
    for (int i = 0; i < 4; ++i) {
        #pragma unroll
        for (int j = 0; j < 4; ++j) {
            int gc = tN + wn * 64 + j * 16 + l15;
            int nloc = gc & 1023;
            int h = nloc >> 6, dk = nloc & 63;
            float bv_ = bias[nloc];
            if (seg == 2) {
                int gr0 = tM + wm * 64 + i * 16 + l4 * 4;
                int bb = gr0 >> 10, s0 = gr0 & 1023;
                short4v pk;
                #pragma unroll
                for (int v = 0; v < 4; ++v) pk[v] = f2bf(acc[i][j][v] + bv_);
                *(short4v*)&outv[(((size_t)bb * 16 + h) * 64 + dk) * 1024 + s0] = pk;
            } else {
                #pragma unroll
                for (int v = 0; v < 4; ++v) {
                    int gr = tM + wm * 64 + i * 16 + l4 * 4 + v;
                    int bb = gr >> 10, s = gr & 1023;
                    float val = acc[i][j][v] + bv_;
                    if (seg == 0) {
                        outq[(((size_t)bb * 16 + h) * 1024 + s) * 64 + dk] = f2bf(val * 0.125f);
                    } else {
                        outk[(((size_t)bb * 16 + h) * 1024 + s) * 64 + dk] = f2bf(val);
                    }
                }
            }
        }
    }
}

// ---------------- O-proj GEMM, 256x256 tile, 16 waves ----------------
// y[4096,1024] = yh @ wob^T + bo. 64 blocks (16M x 4N), XCD-swizzled.
__global__ __launch_bounds__(1024, 1) void gemm_o(const short* __restrict__ A,
                                                  const short* __restrict__ Bw,
                                                  const float* __restrict__ bias,
                                                  float* __restrict__ fout) {
    __shared__ __align__(16) short As[2][256 * 32];
    __shared__ __align__(16) short Bs[2][256 * 32];

    const int tid = threadIdx.x;
    const int wave = tid >> 6, lane = tid & 63;
    const int l15 = lane & 15, l4 = lane >> 4;
    const int wm = wave >> 2, wn = wave & 3;

    const int lin = blockIdx.x;                  // 0..63
    const int swz = (lin & 7) * 8 + (lin >> 3);  // bijective (64 % 8 == 0)
    const int by = swz & 15, bx = swz >> 4;      // M(16) x N(4)
    const int tM = by * 256, tN = bx * 256;

    f32x4 acc[4][4] = {};

    auto stage = [&](int buf, int kt) {
        int e0 = tid * 8;
        int row = e0 >> 5, col = e0 & 31;
        GLD16(&A[(size_t)(tM + row) * 1024 + kt + col],
              (char*)&As[buf][0] + (size_t)tid * 16);
        GLD16(&Bw[(size_t)(tN + row) * 1024 + kt + col],
              (char*)&Bs[buf][0] + (size_t)tid * 16);
    };

    stage(0, 0);
    __syncthreads();
    int cur = 0;

    for (int t = 0; t < 32; ++t) {
        if (t < 31) stage(cur ^ 1, (t + 1) * 32);

        short8 af[4], bfr[4];
        #pragma unroll
        for (int f = 0; f < 4; ++f) {
            af[f]  = *(const short8*)&As[cur][(wm * 64 + f * 16 + l15) * 32 + l4 * 8];
            bfr[f] = *(const short8*)&Bs[cur][(wn * 64 + f * 16 + l15) * 32 + l4 * 8];
        }
        #pragma unroll
        for (int i = 0; i < 4; ++i)
            #pragma unroll
            for (int j = 0; j < 4; ++j)
                acc[i][j] = __builtin_amdgcn_mfma_f32_16x16x32_bf16(af[i], bfr[j], acc[i][j], 0, 0, 0);

        __syncthreads();
        cur ^= 1;
    }

    #pragma unroll
    for (int i = 0; i < 4; ++i) {
        #pragma unroll
        for (int j = 0; j < 4; ++j) {
            #pragma unroll
            for (int v = 0; v < 4; ++v) {
                int gr = tM + wm * 64 + i * 16 + l4 * 4 + v;
                int gc = tN + wn * 64 + j * 16 + l15;
                fout[(size_t)gr * 1024 + gc] = acc[i][j][v] + bias[gc];
            }
        }
    }
}

// ---------------- fused attention (round-12 body, verified 105 µs) ----------
__global__ __launch_bounds__(512, 4) void attn_kernel(const short* __restrict__ q,
                                                      const short* __restrict__ k,
                                                      const short* __restrict__ vT,
                                                      float* __restrict__ attn,
                                                      short* __restrict__ yh) {
    const int bh = blockIdx.x;
    const int y = blockIdx.y;
    const int qb = (y & 1) ? (31 - (y >> 1)) : (y >> 1);
    const int tid = threadIdx.x;
    const int wave = tid >> 6, lane = tid & 63;
    const int l15 = lane & 15, l4 = lane >> 4;
    const int rg = wave & 1, cg = wave >> 1;
    const int q0 = qb * 32;
    const int rbase = q0 + rg * 16;
    const int c0w = cg * 256;

    __shared__ __align__(16) short pb[32][1032];
    __shared__ float mred[4][32];
    __shared__ float sred[4][32];

    short8 qf[2];
    {
        const short* qrow = q + ((size_t)bh * 1024 + rbase + l15) * 64;
        qf[0] = *(const short8*)(qrow + l4 * 8);
        qf[1] = *(const short8*)(qrow + 32 + l4 * 8);
    }

    f32x4 sc[16] = {};
    #pragma unroll
    for (int cf = 0; cf < 16; ++cf) {
        if (c0w + cf * 16 < rbase + 16) {
            const short* krow = k + ((size_t)bh * 1024 + c0w + cf * 16 + l15) * 64;
            short8 kf0 = *(const short8*)(krow + l4 * 8);
            short8 kf1 = *(const short8*)(krow + 32 + l4 * 8);
            sc[cf] = __builtin_amdgcn_mfma_f32_16x16x32_bf16(qf[0], kf0, sc[cf], 0, 0, 0);
            sc[cf] = __builtin_amdgcn_mfma_f32_16x16x32_bf16(qf[1], kf1, sc[cf], 0, 0, 0);
        }
    }

    float mrow[4];
    #pragma unroll
    for (int j = 0; j < 4; ++j) {
        int rglob = rbase + l4 * 4 + j;
        float m = -1e30f;
        #pragma unroll
        for (int cf = 0; cf < 16; ++cf) {
            int col = c0w + cf * 16 + l15;
            m = fmaxf(m, (col <= rglob) ? sc[cf][j] : -1e30f);
        }
        m = fmaxf(m, __shfl_xor(m, 1));
        m = fmaxf(m, __shfl_xor(m, 2));
        m = fmaxf(m, __shfl_xor(m, 4));
        m = fmaxf(m, __shfl_xor(m, 8));
        mrow[j] = m;
    }
    if (l15 == 0) {
        #pragma unroll
        for (int j = 0; j < 4; ++j) mred[cg][rg * 16 + l4 * 4 + j] = mrow[j];
    }
    __syncthreads();
    #pragma unroll
    for (int j = 0; j < 4; ++j) {
        int r = rg * 16 + l4 * 4 + j;
        mrow[j] = fmaxf(fmaxf(mred[0][r], mred[1][r]), fmaxf(mred[2][r], mred[3][r]));
    }

    float inv[4], ls[4];
    #pragma unroll
    for (int j = 0; j < 4; ++j) {
        int rglob = rbase + l4 * 4 + j;
        float s = 0.f;
        #pragma unroll
        for (int cf = 0; cf < 16; ++cf) {
            int col = c0w + cf * 16 + l15;
            float e = (col <= rglob) ? __expf(sc[cf][j] - mrow[j]) : 0.f;
            sc[cf][j] = e;
            s += e;
        }
        s += __shfl_xor(s, 1);
        s += __shfl_xor(s, 2);
        s += __shfl_xor(s, 4);
        s += __shfl_xor(s, 8);
        ls[j] = s;
    }
    if (l15 == 0) {
        #pragma unroll
        for (int j = 0; j < 4; ++j) sred[cg][rg * 16 + l4 * 4 + j] = ls[j];
    }
    __syncthreads();
    #pragma unroll
    for (int j = 0; j < 4; ++j) {
        int r = rg * 16 + l4 * 4 + j;
        inv[j] = 1.0f / (sred[0][r] + sred[1][r] + sred[2][r] + sred[3][r]);
    }

    {
        float* abase = attn + (size_t)bh * 1048576;
        #pragma unroll
        for (int cf = 0; cf < 16; ++cf) {
            const bool keep = (c0w + cf * 16 < q0 + 64);
            const int col = c0w + cf * 16 + l15;
            #pragma unroll
            for (int j = 0; j < 4; ++j) {
                const int row = rg * 16 + l4 * 4 + j;
                float p = sc[cf][j] * inv[j];
                __builtin_nontemporal_store(p, &abase[(size_t)(q0 + row) * 1024 + col]);
                if (keep) pb[row][col] = f2bf(p);
            }
        }
    }
    __syncthreads();

    f32x4 yacc = {};
    {
        const short* vrow = vT + ((size_t)bh * 64 + cg * 16 + l15) * 1024;
        const int nch = (rbase + 16 + 31) >> 5;
        for (int ks = 0; ks < nch; ++ks) {
            short8 pf = *(const short8*)&pb[rg * 16 + l15][ks * 32 + l4 * 8];
            short8 vf = *(const short8*)(vrow + ks * 32 + l4 * 8);
            yacc = __builtin_amdgcn_mfma_f32_16x16x32_bf16(pf, vf, yacc, 0, 0, 0);
        }
    }

    const int b = bh >> 4, h = bh & 15;
    #pragma unroll
    for (int j = 0; j < 4; ++j) {
        yh[((size_t)b * 1024 + rbase + l4 * 4 + j) * 1024 + h * 64 + cg * 16 + l15] = f2bf(yacc[j]);
    }
}

extern "C" void kernel_launch(void* const* d_in, const int* in_sizes, int n_in,
                              void* d_out, int out_size, void* d_ws, size_t ws_size,
                              hipStream_t stream) {
    const float* x  = (const float*)d_in[0];
    const float* Wq = (const float*)d_in[1];
    const float* bq = (const float*)d_in[2];
    const float* Wk = (const float*)d_in[3];
    const float* bk = (const float*)d_in[4];
    const float* Wv = (const float*)d_in[5];
    const float* bv = (const float*)d_in[6];
    const float* Wo = (const float*)d_in[7];
    const float* bo = (const float*)d_in[8];

    char* ws = (char*)d_ws;
    short* xb   = (short*)(ws + ((size_t)0 << 20));
    short* wqkv = (short*)(ws + ((size_t)8 << 20));
    short* wob  = (short*)(ws + ((size_t)14 << 20));
    short* qbp  = (short*)(ws + ((size_t)16 << 20));
    short* kbp  = (short*)(ws + ((size_t)24 << 20));
    short* vTb  = (short*)(ws + ((size_t)32 << 20));
    short* yh   = (short*)(ws + ((size_t)40 << 20));

    float* attn = (float*)d_out;
    float* yout = attn + (size_t)67108864;

    castall_kernel<<<dim3(128, 8), 256, 0, stream>>>(x, Wq, Wk, Wv, Wo, xb, wqkv, wob);

    gemm_qkv256<<<192, 1024, 0, stream>>>(xb, wqkv, bq, bk, bv, qbp, kbp, vTb);

    attn_kernel<<<dim3(64, 32), 512, 0, stream>>>(qbp, kbp, vTb, attn, yh);

    gemm_o<<<64, 1024, 0, stream>>>(yh, wob, bo, yout);
}